// Round 9
// baseline (669.926 us; speedup 1.0000x reference)
//
#include <hip/hip_runtime.h>

#define NT 32
#define EPSF 1e-8f

// ================= Gram kernel =================
// BYTE-IDENTICAL to r10 (verified absmax 0.0). r8 probe: 83us cold vs floors
// {HBM 43, DS-pipe 46, VALU-issue 27}. This round adds PMC probes (below).
#define TILE_COLS 64
#define GR_THREADS 256
#define WAVES_PB 4
#define TILES_PW 8    // cols/wave = 512, cols/block = 2048 -> grid = 1024

__global__ __launch_bounds__(GR_THREADS, 1)
void gram_kernel(const float* __restrict__ vecs, double* __restrict__ Gd, int D)
{
    __shared__ __align__(16) float tile[WAVES_PB][TILE_COLS * 32];
    __shared__ float Gpart[NT * NT];

    const int tid  = threadIdx.x;
    const int wave = tid >> 6;
    const int lane = tid & 63;

    for (int e = tid; e < NT * NT; e += GR_THREADS) Gpart[e] = 0.0f;
    __syncthreads();

    float* my = tile[wave];
    const int swz = lane & 7;

    const int cj = lane >> 4;
    const int pi = (lane >> 2) & 3;
    const int pk = lane & 3;

    float acc[8][8];
#pragma unroll
    for (int r = 0; r < 8; r++)
#pragma unroll
        for (int c = 0; c < 8; c++) acc[r][c] = 0.0f;

    const unsigned base0 = (unsigned)blockIdx.x * (WAVES_PB * TILES_PW * TILE_COLS)
                         + (unsigned)wave * (TILES_PW * TILE_COLS) + (unsigned)lane;

    float pre[32];
#pragma unroll
    for (int r = 0; r < 32; r++)
        pre[r] = (vecs + (size_t)r * (size_t)D)[base0];

    for (int t = 0; t < TILES_PW; t++) {
#pragma unroll
        for (int g = 0; g < 8; g++) {
            float4 w = make_float4(pre[4 * g + 0], pre[4 * g + 1],
                                   pre[4 * g + 2], pre[4 * g + 3]);
            *(float4*)(my + lane * 32 + ((g ^ swz) << 2)) = w;
        }
        if (t + 1 < TILES_PW) {
            const unsigned off = base0 + (unsigned)(t + 1) * TILE_COLS;
#pragma unroll
            for (int r = 0; r < 32; r++)
                pre[r] = (vecs + (size_t)r * (size_t)D)[off];
        }
        asm volatile("" ::: "memory");
#pragma unroll
        for (int jt = 0; jt < 16; jt++) {
            const int j = (jt << 2) + cj;
            const float* col = my + j * 32;
            const int js = j & 7;
            const float4 a0 = *(const float4*)(col + (((2 * pi) ^ js) << 2));
            const float4 a1 = *(const float4*)(col + (((2 * pi + 1) ^ js) << 2));
            const float4 b0 = *(const float4*)(col + (((2 * pk) ^ js) << 2));
            const float4 b1 = *(const float4*)(col + (((2 * pk + 1) ^ js) << 2));
            const float a[8] = {a0.x, a0.y, a0.z, a0.w, a1.x, a1.y, a1.z, a1.w};
            const float b[8] = {b0.x, b0.y, b0.z, b0.w, b1.x, b1.y, b1.z, b1.w};
#pragma unroll
            for (int r = 0; r < 8; r++)
#pragma unroll
                for (int c = 0; c < 8; c++)
                    acc[r][c] = fmaf(a[r], b[c], acc[r][c]);
        }
    }

#pragma unroll
    for (int r = 0; r < 8; r++)
#pragma unroll
        for (int c = 0; c < 8; c++) {
            float v = acc[r][c];
            v += __shfl_xor(v, 16);
            v += __shfl_xor(v, 32);
            if (lane < 16)
                atomicAdd(&Gpart[(8 * pi + r) * NT + (8 * pk + c)], v);
        }
    __syncthreads();
    for (int e = tid; e < NT * NT; e += GR_THREADS)
        atomicAdd(&Gd[e], (double)Gpart[e]);
}

// ===== gram_probe: gram x3 in ONE dispatch (~220us -> surfaces in top-5
// with PMC). Copy-paste (NOT a template: rule #19, co-compiled template
// instantiations perturb each other's regalloc). Writes scratch only. =====
__global__ __launch_bounds__(GR_THREADS, 1)
void gram_probe(const float* __restrict__ vecs, double* __restrict__ Gd, int D)
{
    __shared__ __align__(16) float tile[WAVES_PB][TILE_COLS * 32];
    __shared__ float Gpart[NT * NT];

    const int tid  = threadIdx.x;
    const int wave = tid >> 6;
    const int lane = tid & 63;

    for (int e = tid; e < NT * NT; e += GR_THREADS) Gpart[e] = 0.0f;
    __syncthreads();

    float* my = tile[wave];
    const int swz = lane & 7;
    const int cj = lane >> 4;
    const int pi = (lane >> 2) & 3;
    const int pk = lane & 3;

    float acc[8][8];
#pragma unroll
    for (int r = 0; r < 8; r++)
#pragma unroll
        for (int c = 0; c < 8; c++) acc[r][c] = 0.0f;

    const unsigned base0 = (unsigned)blockIdx.x * (WAVES_PB * TILES_PW * TILE_COLS)
                         + (unsigned)wave * (TILES_PW * TILE_COLS) + (unsigned)lane;

    for (int rep = 0; rep < 3; rep++) {
        float pre[32];
#pragma unroll
        for (int r = 0; r < 32; r++)
            pre[r] = (vecs + (size_t)r * (size_t)D)[base0];

        for (int t = 0; t < TILES_PW; t++) {
#pragma unroll
            for (int g = 0; g < 8; g++) {
                float4 w = make_float4(pre[4 * g + 0], pre[4 * g + 1],
                                       pre[4 * g + 2], pre[4 * g + 3]);
                *(float4*)(my + lane * 32 + ((g ^ swz) << 2)) = w;
            }
            if (t + 1 < TILES_PW) {
                const unsigned off = base0 + (unsigned)(t + 1) * TILE_COLS;
#pragma unroll
                for (int r = 0; r < 32; r++)
                    pre[r] = (vecs + (size_t)r * (size_t)D)[off];
            }
            asm volatile("" ::: "memory");
#pragma unroll
            for (int jt = 0; jt < 16; jt++) {
                const int j = (jt << 2) + cj;
                const float* col = my + j * 32;
                const int js = j & 7;
                const float4 a0 = *(const float4*)(col + (((2 * pi) ^ js) << 2));
                const float4 a1 = *(const float4*)(col + (((2 * pi + 1) ^ js) << 2));
                const float4 b0 = *(const float4*)(col + (((2 * pk) ^ js) << 2));
                const float4 b1 = *(const float4*)(col + (((2 * pk + 1) ^ js) << 2));
                const float a[8] = {a0.x, a0.y, a0.z, a0.w, a1.x, a1.y, a1.z, a1.w};
                const float b[8] = {b0.x, b0.y, b0.z, b0.w, b1.x, b1.y, b1.z, b1.w};
#pragma unroll
                for (int r = 0; r < 8; r++)
#pragma unroll
                    for (int c = 0; c < 8; c++)
                        acc[r][c] = fmaf(a[r], b[c], acc[r][c]);
            }
        }
    }

#pragma unroll
    for (int r = 0; r < 8; r++)
#pragma unroll
        for (int c = 0; c < 8; c++) {
            float v = acc[r][c];
            v += __shfl_xor(v, 16);
            v += __shfl_xor(v, 32);
            if (lane < 16)
                atomicAdd(&Gpart[(8 * pi + r) * NT + (8 * pk + c)], v);
        }
    __syncthreads();
    for (int e = tid; e < NT * NT; e += GR_THREADS)
        atomicAdd(&Gd[e], (double)Gpart[e]);
}

// ================= Solver kernel (BYTE-IDENTICAL r10, verified) =========
template<int CTRL>
__device__ __forceinline__ float dpp0(float x) {
    return __int_as_float(__builtin_amdgcn_update_dpp(
        0, __float_as_int(x), CTRL, 0xF, 0xF, true));
}
template<int CTRL>
__device__ __forceinline__ float dppk(float oldv, float x) {
    return __int_as_float(__builtin_amdgcn_update_dpp(
        __float_as_int(oldv), __float_as_int(x), CTRL, 0xF, 0xF, false));
}
__device__ __forceinline__ float rdlane(float x, int l) {
    return __int_as_float(__builtin_amdgcn_readlane(__float_as_int(x), l));
}

__device__ __forceinline__ float bsum32u(float v) {
    v += dpp0<0x111>(v);
    v += dpp0<0x112>(v);
    v += dpp0<0x114>(v);
    v += dpp0<0x118>(v);
    return rdlane(v, 15) + rdlane(v, 31);
}
__device__ __forceinline__ float bmin32u(float v) {
    v = fminf(v, dppk<0x111>(v, v));
    v = fminf(v, dppk<0x112>(v, v));
    v = fminf(v, dppk<0x114>(v, v));
    v = fminf(v, dppk<0x118>(v, v));
    return fminf(rdlane(v, 15), rdlane(v, 31));
}

// shared body for solver & probe, via macro to guarantee identical code in
// the real kernel while avoiding template-coupled regalloc (rule #19 applies
// to codegen context; the real kernel keeps its own function).
__global__ __launch_bounds__(64)
void solver_kernel(const double* __restrict__ Gd, float* __restrict__ out)
{
    __shared__ float Gsh[NT * 33];
    __shared__ __align__(16) float xb0[64];
    __shared__ __align__(16) float xb1[64];
    __shared__ __align__(16) float xb2[64];

    const int lane = threadIdx.x;
    const int e = lane & 31;
    const int h = lane >> 5;

    for (int t2 = 0; t2 < 16; t2++) {
        int idx = t2 * 64 + lane;
        Gsh[(idx >> 5) * 33 + (idx & 31)] = (float)Gd[idx];
    }
    __syncthreads();

    float Grow[16];
#pragma unroll
    for (int k = 0; k < 16; k++)
        Grow[k] = Gsh[e * 33 + 16 * h + k];

    const int hb = h * 48;
    const float4* xr0 = (const float4*)(xb0 + hb);
    const float4* xr1 = (const float4*)(xb1 + hb);
    const float4* xr2 = (const float4*)(xb2 + hb);

    auto mv = [&](const float4* xr) -> float {
        const float4 q0 = xr[0], q1 = xr[1], q2 = xr[2], q3 = xr[3];
        const float xv[16] = {q0.x, q0.y, q0.z, q0.w, q1.x, q1.y, q1.z, q1.w,
                              q2.x, q2.y, q2.z, q2.w, q3.x, q3.y, q3.z, q3.w};
        float a0 = 0.0f, a1 = 0.0f;
#pragma unroll
        for (int s = 0; s < 16; s += 2) {
            a0 = fmaf(Grow[s + 0], xv[s + 0], a0);
            a1 = fmaf(Grow[s + 1], xv[s + 1], a1);
        }
        float half = a0 + a1;
        return half + __shfl_xor(half, 32);
    };

    float bestCost = INFINITY, bestGamma = 0.0f;
    int bestEnc = 0x7FFFFFFF;
    for (int a = 0; a < NT - 1; a++) {
        int b = a + 1 + lane;
        if (b < NT) {
            float v11 = Gsh[a * 33 + a];
            float v12 = Gsh[a * 33 + b];
            float v22 = Gsh[b * 33 + b];
            float g = (v22 - v12) / (v11 + v22 - 2.0f * v12 + EPSF);
            float c = v22 + g * (v12 - v22);
            float gamma = (v12 >= v22) ? 0.0f : g;
            float cost  = (v12 >= v22) ? v22 : c;
            if (v12 >= v11) { gamma = 1.0f; cost = v11; }
            int enc = a * NT + b;
            if (cost < bestCost) { bestCost = cost; bestEnc = enc; bestGamma = gamma; }
        }
    }
#pragma unroll
    for (int m = 1; m < 64; m <<= 1) {
        float oc = __shfl_xor(bestCost, m);
        int   oe = __shfl_xor(bestEnc, m);
        float og = __shfl_xor(bestGamma, m);
        if (oc < bestCost || (oc == bestCost && oe < bestEnc)) {
            bestCost = oc; bestEnc = oe; bestGamma = og;
        }
    }
    const int bi = bestEnc >> 5, bj = bestEnc & 31;

    float sol = 0.0f;
    if (e == bi) sol = bestGamma;
    if (e == bj) sol = 1.0f - bestGamma;

    xb0[lane] = sol;

    for (int it = 0; it < 250; it++) {
        float Gsol = mv(xr0);

        float grad = -Gsol;
        float proj = grad - bsum32u(grad) * 0.03125f;

        float tm1 = (proj < 0.0f) ? (-sol / proj) : INFINITY;
        float tm2 = (proj > 0.0f) ? ((1.0f - sol) / proj) : INFINITY;
        float m1 = bmin32u((tm1 > 1e-7f) ? tm1 : INFINITY);
        float m2 = bmin32u((tm2 > 1e-7f) ? tm2 : INFINITY);
        float t = __builtin_isinf(m1) ? 1.0f : m1;
        t = fminf(t, m2);
        float nxt = fmaf(proj, t, sol);

        int nb = __float_as_int(nxt);
        unsigned u = (unsigned)nb ^ ((nb < 0) ? 0xFFFFFFFFu : 0x80000000u);

        xb1[lane] = nxt;
        const float4 r0 = xr1[0], r1 = xr1[1], r2 = xr1[2], r3 = xr1[3];
        const float xj16[16] = {r0.x, r0.y, r0.z, r0.w, r1.x, r1.y, r1.z, r1.w,
                                r2.x, r2.y, r2.z, r2.w, r3.x, r3.y, r3.z, r3.w};

        int rank = 0;
        float S = 0.0f;
        const int dtie = e - 16 * h;
#pragma unroll
        for (int s = 0; s < 16; s++) {
            float xj = xj16[s];
            int nbj = __float_as_int(xj);
            unsigned uj = (unsigned)nbj ^ ((nbj < 0) ? 0xFFFFFFFFu : 0x80000000u);
            bool gt = (uj > u) || ((uj == u) && (s < dtie));
            rank += gt ? 1 : 0;
            S += gt ? xj : 0.0f;
        }
        rank += __shfl_xor(rank, 32);
        S += __shfl_xor(S, 32);

        float total = bsum32u(nxt);

        float cand = (S - 1.0f) / (float)rank;
        bool cond = (rank >= 1) && (cand > nxt);
        float rmin = bmin32u(cond ? (float)rank : INFINITY);
        unsigned long long msk = __ballot(cond && ((float)rank == rmin));
        int src = (int)__ffsll(msk) - 1;
        float tmax = (msk == 0ull)
                   ? (total - 1.0f) * 0.03125f
                   : rdlane(cand, src);
        float newp = fmaxf(nxt - tmax, 0.0f);

        xb2[lane] = newp;
        float Gn = mv(xr2);

        float z = (h == 0) ? (sol * Gsol) : (newp * Gn);
        z += dpp0<0x111>(z);
        z += dpp0<0x112>(z);
        z += dpp0<0x114>(z);
        z += dpp0<0x118>(z);
        float v11 = rdlane(z, 15) + rdlane(z, 31);
        float v22 = rdlane(z, 47) + rdlane(z, 63);
        float v12 = bsum32u(sol * Gn);

        float g = (v22 - v12) / (v11 + v22 - 2.0f * v12 + EPSF);
        float gamma = (v12 >= v22) ? 0.0f : g;
        gamma = (v12 >= v11) ? 1.0f : gamma;

        float new_sol = gamma * sol + (1.0f - gamma) * newp;
        float diff = bsum32u(fabsf(new_sol - sol));
        if (diff < 1e-6f) break;
        sol = new_sol;
        xb0[lane] = sol;
    }
    if (lane < NT) out[lane] = sol;
}

// ===== solver_probe: solver x2 per block, grid=256 (1 block/CU) so the
// GPU-wide VALUBusy % equals the per-wave busy fraction. ~310us -> top-5.
// Writes scratch only (per-block, per-rep offsets defeat DCE/CSE). =====
__global__ __launch_bounds__(64)
void solver_probe(const double* __restrict__ Gd, float* __restrict__ out2)
{
    __shared__ float Gsh[NT * 33];
    __shared__ __align__(16) float xb0[64];
    __shared__ __align__(16) float xb1[64];
    __shared__ __align__(16) float xb2[64];

    const int lane = threadIdx.x;
    const int e = lane & 31;
    const int h = lane >> 5;

    for (int rep = 0; rep < 2; rep++) {
        for (int t2 = 0; t2 < 16; t2++) {
            int idx = t2 * 64 + lane;
            Gsh[(idx >> 5) * 33 + (idx & 31)] = (float)Gd[idx];
        }
        __syncthreads();

        float Grow[16];
#pragma unroll
        for (int k = 0; k < 16; k++)
            Grow[k] = Gsh[e * 33 + 16 * h + k];

        const int hb = h * 48;
        const float4* xr0 = (const float4*)(xb0 + hb);
        const float4* xr1 = (const float4*)(xb1 + hb);
        const float4* xr2 = (const float4*)(xb2 + hb);

        auto mv = [&](const float4* xr) -> float {
            const float4 q0 = xr[0], q1 = xr[1], q2 = xr[2], q3 = xr[3];
            const float xv[16] = {q0.x, q0.y, q0.z, q0.w, q1.x, q1.y, q1.z, q1.w,
                                  q2.x, q2.y, q2.z, q2.w, q3.x, q3.y, q3.z, q3.w};
            float a0 = 0.0f, a1 = 0.0f;
#pragma unroll
            for (int s = 0; s < 16; s += 2) {
                a0 = fmaf(Grow[s + 0], xv[s + 0], a0);
                a1 = fmaf(Grow[s + 1], xv[s + 1], a1);
            }
            float half = a0 + a1;
            return half + __shfl_xor(half, 32);
        };

        float bestCost = INFINITY, bestGamma = 0.0f;
        int bestEnc = 0x7FFFFFFF;
        for (int a = 0; a < NT - 1; a++) {
            int b = a + 1 + lane;
            if (b < NT) {
                float v11 = Gsh[a * 33 + a];
                float v12 = Gsh[a * 33 + b];
                float v22 = Gsh[b * 33 + b];
                float g = (v22 - v12) / (v11 + v22 - 2.0f * v12 + EPSF);
                float c = v22 + g * (v12 - v22);
                float gamma = (v12 >= v22) ? 0.0f : g;
                float cost  = (v12 >= v22) ? v22 : c;
                if (v12 >= v11) { gamma = 1.0f; cost = v11; }
                int enc = a * NT + b;
                if (cost < bestCost) { bestCost = cost; bestEnc = enc; bestGamma = gamma; }
            }
        }
#pragma unroll
        for (int m = 1; m < 64; m <<= 1) {
            float oc = __shfl_xor(bestCost, m);
            int   oe = __shfl_xor(bestEnc, m);
            float og = __shfl_xor(bestGamma, m);
            if (oc < bestCost || (oc == bestCost && oe < bestEnc)) {
                bestCost = oc; bestEnc = oe; bestGamma = og;
            }
        }
        const int bi = bestEnc >> 5, bj = bestEnc & 31;

        float sol = 0.0f;
        if (e == bi) sol = bestGamma;
        if (e == bj) sol = 1.0f - bestGamma;

        xb0[lane] = sol;

        for (int it = 0; it < 250; it++) {
            float Gsol = mv(xr0);
            float grad = -Gsol;
            float proj = grad - bsum32u(grad) * 0.03125f;

            float tm1 = (proj < 0.0f) ? (-sol / proj) : INFINITY;
            float tm2 = (proj > 0.0f) ? ((1.0f - sol) / proj) : INFINITY;
            float m1 = bmin32u((tm1 > 1e-7f) ? tm1 : INFINITY);
            float m2 = bmin32u((tm2 > 1e-7f) ? tm2 : INFINITY);
            float t = __builtin_isinf(m1) ? 1.0f : m1;
            t = fminf(t, m2);
            float nxt = fmaf(proj, t, sol);

            int nb = __float_as_int(nxt);
            unsigned u = (unsigned)nb ^ ((nb < 0) ? 0xFFFFFFFFu : 0x80000000u);

            xb1[lane] = nxt;
            const float4 r0 = xr1[0], r1 = xr1[1], r2 = xr1[2], r3 = xr1[3];
            const float xj16[16] = {r0.x, r0.y, r0.z, r0.w, r1.x, r1.y, r1.z, r1.w,
                                    r2.x, r2.y, r2.z, r2.w, r3.x, r3.y, r3.z, r3.w};

            int rank = 0;
            float S = 0.0f;
            const int dtie = e - 16 * h;
#pragma unroll
            for (int s = 0; s < 16; s++) {
                float xj = xj16[s];
                int nbj = __float_as_int(xj);
                unsigned uj = (unsigned)nbj ^ ((nbj < 0) ? 0xFFFFFFFFu : 0x80000000u);
                bool gt = (uj > u) || ((uj == u) && (s < dtie));
                rank += gt ? 1 : 0;
                S += gt ? xj : 0.0f;
            }
            rank += __shfl_xor(rank, 32);
            S += __shfl_xor(S, 32);

            float total = bsum32u(nxt);

            float cand = (S - 1.0f) / (float)rank;
            bool cond = (rank >= 1) && (cand > nxt);
            float rmin = bmin32u(cond ? (float)rank : INFINITY);
            unsigned long long msk = __ballot(cond && ((float)rank == rmin));
            int src = (int)__ffsll(msk) - 1;
            float tmax = (msk == 0ull)
                       ? (total - 1.0f) * 0.03125f
                       : rdlane(cand, src);
            float newp = fmaxf(nxt - tmax, 0.0f);

            xb2[lane] = newp;
            float Gn = mv(xr2);

            float z = (h == 0) ? (sol * Gsol) : (newp * Gn);
            z += dpp0<0x111>(z);
            z += dpp0<0x112>(z);
            z += dpp0<0x114>(z);
            z += dpp0<0x118>(z);
            float v11 = rdlane(z, 15) + rdlane(z, 31);
            float v22 = rdlane(z, 47) + rdlane(z, 63);
            float v12 = bsum32u(sol * Gn);

            float g = (v22 - v12) / (v11 + v22 - 2.0f * v12 + EPSF);
            float gamma = (v12 >= v22) ? 0.0f : g;
            gamma = (v12 >= v11) ? 1.0f : gamma;

            float new_sol = gamma * sol + (1.0f - gamma) * newp;
            float diff = bsum32u(fabsf(new_sol - sol));
            if (diff < 1e-6f) break;
            sol = new_sol;
            xb0[lane] = sol;
        }
        if (lane < NT)
            out2[(size_t)blockIdx.x * 64 + rep * 32 + lane] = sol;
        __syncthreads();
    }
}

extern "C" void kernel_launch(void* const* d_in, const int* in_sizes, int n_in,
                              void* d_out, int out_size, void* d_ws, size_t ws_size,
                              hipStream_t stream) {
    const float* vecs = (const float*)d_in[0];
    float* out = (float*)d_out;
    double* Gd = (double*)d_ws;          // 1024 doubles = 8 KB
    const int D = in_sizes[0] / NT;      // 2097152

    hipMemsetAsync(Gd, 0, NT * NT * sizeof(double), stream);

    const int cols_per_block = WAVES_PB * TILES_PW * TILE_COLS;  // 2048
    const int grid = D / cols_per_block;                          // 1024
    gram_kernel<<<grid, GR_THREADS, 0, stream>>>(vecs, Gd, D);
    solver_kernel<<<1, 64, 0, stream>>>(Gd, out);

    // ==== r11 PMC PROBES (one round only; removed next round). Scratch: ====
    double* Gd2  = (double*)((char*)d_ws + 8192);           // gram_probe acc
    float*  out2 = (float*)((char*)d_ws + (1 << 20));       // solver_probe out
    gram_probe<<<grid, GR_THREADS, 0, stream>>>(vecs, Gd2, D);
    solver_probe<<<256, 64, 0, stream>>>(Gd, out2);
}

// Round 10
// 409.709 us; speedup vs baseline: 1.6351x; 1.6351x over previous
//
#include <hip/hip_runtime.h>

#define NT 32
#define EPSF 1e-8f

// ================= Gram kernel =================
// BYTE-IDENTICAL to r10 (verified absmax 0.0). r11 PMC probe: ~88us/rep,
// VALUBusy 49%, bank-conflict 0, VGPR 168 (3 waves/SIMD), L3-warm reps NOT
// faster -> internally bound (DS 46us + VALU 32us, poorly overlapped).
// Headroom ~40us requires VGPR<=128 (structurally blocked: pre[32] IS the
// double buffer; LDS dbuf would halve block residency) or bf16-MFMA rewrite
// (queued as the pivot if solver chain-cut nulls).
#define TILE_COLS 64
#define GR_THREADS 256
#define WAVES_PB 4
#define TILES_PW 8    // cols/wave = 512, cols/block = 2048 -> grid = 1024

__global__ __launch_bounds__(GR_THREADS, 1)
void gram_kernel(const float* __restrict__ vecs, double* __restrict__ Gd, int D)
{
    __shared__ __align__(16) float tile[WAVES_PB][TILE_COLS * 32];
    __shared__ float Gpart[NT * NT];

    const int tid  = threadIdx.x;
    const int wave = tid >> 6;
    const int lane = tid & 63;

    for (int e = tid; e < NT * NT; e += GR_THREADS) Gpart[e] = 0.0f;
    __syncthreads();

    float* my = tile[wave];
    const int swz = lane & 7;

    const int cj = lane >> 4;
    const int pi = (lane >> 2) & 3;
    const int pk = lane & 3;

    float acc[8][8];
#pragma unroll
    for (int r = 0; r < 8; r++)
#pragma unroll
        for (int c = 0; c < 8; c++) acc[r][c] = 0.0f;

    const unsigned base0 = (unsigned)blockIdx.x * (WAVES_PB * TILES_PW * TILE_COLS)
                         + (unsigned)wave * (TILES_PW * TILE_COLS) + (unsigned)lane;

    float pre[32];
#pragma unroll
    for (int r = 0; r < 32; r++)
        pre[r] = (vecs + (size_t)r * (size_t)D)[base0];

    for (int t = 0; t < TILES_PW; t++) {
#pragma unroll
        for (int g = 0; g < 8; g++) {
            float4 w = make_float4(pre[4 * g + 0], pre[4 * g + 1],
                                   pre[4 * g + 2], pre[4 * g + 3]);
            *(float4*)(my + lane * 32 + ((g ^ swz) << 2)) = w;
        }
        if (t + 1 < TILES_PW) {
            const unsigned off = base0 + (unsigned)(t + 1) * TILE_COLS;
#pragma unroll
            for (int r = 0; r < 32; r++)
                pre[r] = (vecs + (size_t)r * (size_t)D)[off];
        }
        asm volatile("" ::: "memory");
#pragma unroll
        for (int jt = 0; jt < 16; jt++) {
            const int j = (jt << 2) + cj;
            const float* col = my + j * 32;
            const int js = j & 7;
            const float4 a0 = *(const float4*)(col + (((2 * pi) ^ js) << 2));
            const float4 a1 = *(const float4*)(col + (((2 * pi + 1) ^ js) << 2));
            const float4 b0 = *(const float4*)(col + (((2 * pk) ^ js) << 2));
            const float4 b1 = *(const float4*)(col + (((2 * pk + 1) ^ js) << 2));
            const float a[8] = {a0.x, a0.y, a0.z, a0.w, a1.x, a1.y, a1.z, a1.w};
            const float b[8] = {b0.x, b0.y, b0.z, b0.w, b1.x, b1.y, b1.z, b1.w};
#pragma unroll
            for (int r = 0; r < 8; r++)
#pragma unroll
                for (int c = 0; c < 8; c++)
                    acc[r][c] = fmaf(a[r], b[c], acc[r][c]);
        }
    }

#pragma unroll
    for (int r = 0; r < 8; r++)
#pragma unroll
        for (int c = 0; c < 8; c++) {
            float v = acc[r][c];
            v += __shfl_xor(v, 16);
            v += __shfl_xor(v, 32);
            if (lane < 16)
                atomicAdd(&Gpart[(8 * pi + r) * NT + (8 * pk + c)], v);
        }
    __syncthreads();
    for (int e = tid; e < NT * NT; e += GR_THREADS)
        atomicAdd(&Gd[e], (double)Gpart[e]);
}

// ================= Solver kernel =================
// r12: FIRST structural chain cut. Budget (r8+r11): solver ~155us = 250 full
// iterations x ~1490cy serial chain (never converges on this input). Four
// prior nulls (r6/r9/r10) changed instruction counts, not the chain.
// Recurrence: new_sol = g*sol + (1-g)*newp  =>  G.new_sol = g*Gsol + (1-g)*Gn
// (both in registers) -- replaces the leading matvec (~350cy of LDS write ->
// b128 reads -> lgkm -> 8-FMA chain -> xor32) with 2 FMAs on 3 of every 4
// iterations. EXACT refresh every 4th iter bounds drift: old r4 full
// recurrence (250-step drift) hit absmax 2.4e-4; linear scaling -> refresh-4
// drift ~3e-6. Mirroring preserved (Gsol/Gn/gamma all mirrored).
// Everything else byte-identical to the verified r10 solver.
template<int CTRL>
__device__ __forceinline__ float dpp0(float x) {
    return __int_as_float(__builtin_amdgcn_update_dpp(
        0, __float_as_int(x), CTRL, 0xF, 0xF, true));
}
template<int CTRL>
__device__ __forceinline__ float dppk(float oldv, float x) {
    return __int_as_float(__builtin_amdgcn_update_dpp(
        __float_as_int(oldv), __float_as_int(x), CTRL, 0xF, 0xF, false));
}
__device__ __forceinline__ float rdlane(float x, int l) {
    return __int_as_float(__builtin_amdgcn_readlane(__float_as_int(x), l));
}

__device__ __forceinline__ float bsum32u(float v) {
    v += dpp0<0x111>(v);
    v += dpp0<0x112>(v);
    v += dpp0<0x114>(v);
    v += dpp0<0x118>(v);
    return rdlane(v, 15) + rdlane(v, 31);
}
__device__ __forceinline__ float bmin32u(float v) {
    v = fminf(v, dppk<0x111>(v, v));
    v = fminf(v, dppk<0x112>(v, v));
    v = fminf(v, dppk<0x114>(v, v));
    v = fminf(v, dppk<0x118>(v, v));
    return fminf(rdlane(v, 15), rdlane(v, 31));
}

__global__ __launch_bounds__(64)
void solver_kernel(const double* __restrict__ Gd, float* __restrict__ out)
{
    __shared__ float Gsh[NT * 33];
    __shared__ __align__(16) float xb0[64];
    __shared__ __align__(16) float xb1[64];
    __shared__ __align__(16) float xb2[64];

    const int lane = threadIdx.x;
    const int e = lane & 31;
    const int h = lane >> 5;

    for (int t2 = 0; t2 < 16; t2++) {
        int idx = t2 * 64 + lane;
        Gsh[(idx >> 5) * 33 + (idx & 31)] = (float)Gd[idx];
    }
    __syncthreads();

    float Grow[16];
#pragma unroll
    for (int k = 0; k < 16; k++)
        Grow[k] = Gsh[e * 33 + 16 * h + k];

    const int hb = h * 48;
    const float4* xr0 = (const float4*)(xb0 + hb);
    const float4* xr1 = (const float4*)(xb1 + hb);
    const float4* xr2 = (const float4*)(xb2 + hb);

    auto mv = [&](const float4* xr) -> float {
        const float4 q0 = xr[0], q1 = xr[1], q2 = xr[2], q3 = xr[3];
        const float xv[16] = {q0.x, q0.y, q0.z, q0.w, q1.x, q1.y, q1.z, q1.w,
                              q2.x, q2.y, q2.z, q2.w, q3.x, q3.y, q3.z, q3.w};
        float a0 = 0.0f, a1 = 0.0f;
#pragma unroll
        for (int s = 0; s < 16; s += 2) {
            a0 = fmaf(Grow[s + 0], xv[s + 0], a0);
            a1 = fmaf(Grow[s + 1], xv[s + 1], a1);
        }
        float half = a0 + a1;
        return half + __shfl_xor(half, 32);
    };

    float bestCost = INFINITY, bestGamma = 0.0f;
    int bestEnc = 0x7FFFFFFF;
    for (int a = 0; a < NT - 1; a++) {
        int b = a + 1 + lane;
        if (b < NT) {
            float v11 = Gsh[a * 33 + a];
            float v12 = Gsh[a * 33 + b];
            float v22 = Gsh[b * 33 + b];
            float g = (v22 - v12) / (v11 + v22 - 2.0f * v12 + EPSF);
            float c = v22 + g * (v12 - v22);
            float gamma = (v12 >= v22) ? 0.0f : g;
            float cost  = (v12 >= v22) ? v22 : c;
            if (v12 >= v11) { gamma = 1.0f; cost = v11; }
            int enc = a * NT + b;
            if (cost < bestCost) { bestCost = cost; bestEnc = enc; bestGamma = gamma; }
        }
    }
#pragma unroll
    for (int m = 1; m < 64; m <<= 1) {
        float oc = __shfl_xor(bestCost, m);
        int   oe = __shfl_xor(bestEnc, m);
        float og = __shfl_xor(bestGamma, m);
        if (oc < bestCost || (oc == bestCost && oe < bestEnc)) {
            bestCost = oc; bestEnc = oe; bestGamma = og;
        }
    }
    const int bi = bestEnc >> 5, bj = bestEnc & 31;

    float sol = 0.0f;
    if (e == bi) sol = bestGamma;
    if (e == bj) sol = 1.0f - bestGamma;

    xb0[lane] = sol;

    float GsolRec = 0.0f;    // valid when (it & 3) != 0

    for (int it = 0; it < 250; it++) {
        // exact matvec every 4th iteration; recurrence otherwise (drift <= 3
        // steps of fp32 rounding, ~3e-6 worst case vs r4's 250-step 2.4e-4)
        float Gsol = ((it & 3) == 0) ? mv(xr0) : GsolRec;

        float grad = -Gsol;
        float proj = grad - bsum32u(grad) * 0.03125f;

        float tm1 = (proj < 0.0f) ? (-sol / proj) : INFINITY;
        float tm2 = (proj > 0.0f) ? ((1.0f - sol) / proj) : INFINITY;
        float m1 = bmin32u((tm1 > 1e-7f) ? tm1 : INFINITY);
        float m2 = bmin32u((tm2 > 1e-7f) ? tm2 : INFINITY);
        float t = __builtin_isinf(m1) ? 1.0f : m1;
        t = fminf(t, m2);
        float nxt = fmaf(proj, t, sol);

        int nb = __float_as_int(nxt);
        unsigned u = (unsigned)nb ^ ((nb < 0) ? 0xFFFFFFFFu : 0x80000000u);

        xb1[lane] = nxt;
        const float4 r0 = xr1[0], r1 = xr1[1], r2 = xr1[2], r3 = xr1[3];
        const float xj16[16] = {r0.x, r0.y, r0.z, r0.w, r1.x, r1.y, r1.z, r1.w,
                                r2.x, r2.y, r2.z, r2.w, r3.x, r3.y, r3.z, r3.w};

        int rank = 0;
        float S = 0.0f;
        const int dtie = e - 16 * h;
#pragma unroll
        for (int s = 0; s < 16; s++) {
            float xj = xj16[s];
            int nbj = __float_as_int(xj);
            unsigned uj = (unsigned)nbj ^ ((nbj < 0) ? 0xFFFFFFFFu : 0x80000000u);
            bool gt = (uj > u) || ((uj == u) && (s < dtie));
            rank += gt ? 1 : 0;
            S += gt ? xj : 0.0f;
        }
        rank += __shfl_xor(rank, 32);
        S += __shfl_xor(S, 32);

        float total = bsum32u(nxt);

        float cand = (S - 1.0f) / (float)rank;
        bool cond = (rank >= 1) && (cand > nxt);
        float rmin = bmin32u(cond ? (float)rank : INFINITY);
        unsigned long long msk = __ballot(cond && ((float)rank == rmin));
        int src = (int)__ffsll(msk) - 1;
        float tmax = (msk == 0ull)
                   ? (total - 1.0f) * 0.03125f
                   : rdlane(cand, src);
        float newp = fmaxf(nxt - tmax, 0.0f);

        xb2[lane] = newp;
        float Gn = mv(xr2);

        float z = (h == 0) ? (sol * Gsol) : (newp * Gn);
        z += dpp0<0x111>(z);
        z += dpp0<0x112>(z);
        z += dpp0<0x114>(z);
        z += dpp0<0x118>(z);
        float v11 = rdlane(z, 15) + rdlane(z, 31);
        float v22 = rdlane(z, 47) + rdlane(z, 63);
        float v12 = bsum32u(sol * Gn);

        float g = (v22 - v12) / (v11 + v22 - 2.0f * v12 + EPSF);
        float gamma = (v12 >= v22) ? 0.0f : g;
        gamma = (v12 >= v11) ? 1.0f : gamma;

        float new_sol = gamma * sol + (1.0f - gamma) * newp;

        // G.new_sol by linearity (exact in real arithmetic; fp32 here)
        GsolRec = fmaf(gamma, Gsol, (1.0f - gamma) * Gn);

        float diff = bsum32u(fabsf(new_sol - sol));
        if (diff < 1e-6f) break;
        sol = new_sol;
        xb0[lane] = sol;
    }
    if (lane < NT) out[lane] = sol;
}

extern "C" void kernel_launch(void* const* d_in, const int* in_sizes, int n_in,
                              void* d_out, int out_size, void* d_ws, size_t ws_size,
                              hipStream_t stream) {
    const float* vecs = (const float*)d_in[0];
    float* out = (float*)d_out;
    double* Gd = (double*)d_ws;          // 1024 doubles = 8 KB
    const int D = in_sizes[0] / NT;      // 2097152

    hipMemsetAsync(Gd, 0, NT * NT * sizeof(double), stream);

    const int cols_per_block = WAVES_PB * TILES_PW * TILE_COLS;  // 2048
    const int grid = D / cols_per_block;                          // 1024
    gram_kernel<<<grid, GR_THREADS, 0, stream>>>(vecs, Gd, D);
    solver_kernel<<<1, 64, 0, stream>>>(Gd, out);
}